// Round 3
// baseline (142.048 us; speedup 1.0000x reference)
//
#include <hip/hip_runtime.h>
#include <stdint.h>

// Problem geometry
#define DD    64          // slices
#define HH    512         // rows
#define WWID  512         // cols
#define WPR   8           // u64 words per row (512 bits)
#define NSUB  48          // 24 scan iters x 2 sub-iterations
#define BANDS 4           // row-bands per slice
#define BH    128         // output rows per band
#define HALO  52          // 48 (thinning) + 4 (closing: dilate 2 + erode 2)
#define MAXR  (BH + 2*HALO)   // 232 rows max loaded
#define LDSW  9           // padded row pitch in words (break bank striding)

typedef unsigned long long u64;

// ---------------- kernel 1: threshold + bit-pack via ballot ----------------
__global__ void pack_kernel(const float* __restrict__ in, u64* __restrict__ bits) {
    long gid  = (long)blockIdx.x * blockDim.x + threadIdx.x;
    long wv   = gid >> 6;
    int  lane = (int)(gid & 63);
    long base = wv * 256;
    #pragma unroll
    for (int k = 0; k < 4; ++k) {
        float v = in[base + (long)k * 64 + lane];
        u64 m = __ballot(v > 0.5f);
        if (lane == 0) bits[wv * 4 + k] = m;
    }
}

// bit-sliced full/half adders
__device__ __forceinline__ void fadd(u64 a, u64 b, u64 c, u64& s, u64& co) {
    u64 t = a ^ b;
    s  = t ^ c;
    co = (a & b) | (t & c);
}
__device__ __forceinline__ void hadd(u64 a, u64 b, u64& s, u64& co) {
    s = a ^ b; co = a & b;
}

// ---------------- kernel 2: closing + 48x thinning in LDS ----------------
// One block per (slice, band). 512 threads: 2 threads per row, 4 words each.
__global__ __launch_bounds__(512, 1)
void thin_kernel(const u64* __restrict__ bits, int* __restrict__ out) {
    __shared__ u64 bufA[MAXR][LDSW];
    __shared__ u64 bufB[MAXR][LDSW];

    const int blk  = blockIdx.x;
    const int z    = blk >> 2;       // slice
    const int band = blk & 3;
    const int r0   = band * BH;      // first output row
    const int la   = (r0 - HALO > 0) ? (r0 - HALO) : 0;
    const int lb   = (r0 + BH + HALO < HH) ? (r0 + BH + HALO) : HH;
    const int nrows = lb - la;       // rows resident in LDS (<= 232)

    const int t  = threadIdx.x;
    const int lr = t >> 1;           // local row handled by this thread
    const int h4 = (t & 1) * 4;      // word offset: 0 or 4

    u64 (*cur)[LDSW] = bufA;
    u64 (*nxt)[LDSW] = bufB;

    // ---- load packed raw mask into cur ----
    if (lr < nrows) {
        const u64* src = bits + ((long)(z * HH + la + lr)) * WPR + h4;
        #pragma unroll
        for (int j = 0; j < 4; ++j) cur[lr][h4 + j] = src[j];
    }
    __syncthreads();

    // ---- closing: dilation then erosion with disk(2) (13-pt footprint) ----
    #pragma unroll 1
    for (int phase = 0; phase < 2; ++phase) {   // 0 = dilation (OR), 1 = erosion (AND)
        if (lr < nrows) {
            u64 C[6], U[6], Dn[6], U2[4], D2[4];
            #pragma unroll
            for (int i = 0; i < 6; ++i) {
                int wi = h4 - 1 + i;
                bool okw = (wi >= 0) & (wi < WPR);
                C[i]  = okw ? cur[lr][wi] : 0ull;
                U[i]  = (okw && lr >= 1)        ? cur[lr - 1][wi] : 0ull;
                Dn[i] = (okw && lr + 1 < nrows) ? cur[lr + 1][wi] : 0ull;
            }
            #pragma unroll
            for (int j = 0; j < 4; ++j) {
                int wi = h4 + j;
                U2[j] = (lr >= 2)        ? cur[lr - 2][wi] : 0ull;
                D2[j] = (lr + 2 < nrows) ? cur[lr + 2][wi] : 0ull;
            }
            #pragma unroll
            for (int j = 0; j < 4; ++j) {
                u64 c  = C[j + 1], pl = C[j], pr = C[j + 2];
                u64 l1 = (c << 1) | (pl >> 63);
                u64 l2 = (c << 2) | (pl >> 62);
                u64 r1 = (c >> 1) | (pr << 63);
                u64 r2 = (c >> 2) | (pr << 62);
                u64 u  = U[j + 1];
                u64 ul = (u << 1) | (U[j] >> 63);
                u64 ur = (u >> 1) | (U[j + 2] << 63);
                u64 d  = Dn[j + 1];
                u64 dl = (d << 1) | (Dn[j] >> 63);
                u64 dr = (d >> 1) | (Dn[j + 2] << 63);
                u64 res;
                if (phase == 0)
                    res = c | l1 | l2 | r1 | r2 | u | ul | ur | d | dl | dr | U2[j] | D2[j];
                else
                    res = c & l1 & l2 & r1 & r2 & u & ul & ur & d & dl & dr & U2[j] & D2[j];
                nxt[lr][h4 + j] = res;
            }
        }
        __syncthreads();
        u64 (*tmp)[LDSW] = cur; cur = nxt; nxt = tmp;
    }

    // ---- 48 Zhang-Suen sub-iterations, bit-sliced ----
    auto subiter = [&](int step) {
        if (lr < nrows) {
            u64 C[6], U[6], Dn[6];
            #pragma unroll
            for (int i = 0; i < 6; ++i) {
                int wi = h4 - 1 + i;
                bool okw = (wi >= 0) & (wi < WPR);
                C[i]  = okw ? cur[lr][wi] : 0ull;
                U[i]  = (okw && lr >= 1)        ? cur[lr - 1][wi] : 0ull;
                Dn[i] = (okw && lr + 1 < nrows) ? cur[lr + 1][wi] : 0ull;
            }
            #pragma unroll
            for (int j = 0; j < 4; ++j) {
                u64 c  = C[j + 1];
                u64 N  = U[j + 1];
                u64 S  = Dn[j + 1];
                u64 E  = (C[j + 1] >> 1)  | (C[j + 2] << 63);
                u64 Wn = (C[j + 1] << 1)  | (C[j]     >> 63);
                u64 NE = (U[j + 1] >> 1)  | (U[j + 2] << 63);
                u64 NW = (U[j + 1] << 1)  | (U[j]     >> 63);
                u64 SE = (Dn[j + 1] >> 1) | (Dn[j + 2] << 63);
                u64 SW = (Dn[j + 1] << 1) | (Dn[j]    >> 63);
                // P2..P9 = N,NE,E,SE,S,SW,W,NW
                u64 p[8] = {N, NE, E, SE, S, SW, Wn, NW};
                // A == 1: exactly one 0->1 transition around the ring
                u64 one = 0, two = 0;
                #pragma unroll
                for (int k = 0; k < 8; ++k) {
                    u64 tk = ~p[k] & p[(k + 1) & 7];
                    two |= one & tk;
                    one |= tk;
                }
                u64 A1 = one & ~two;
                // B = popcount(P2..P9) per pixel, bit-sliced CSA
                u64 sa, ca, sb, cb2, sc, cc;
                fadd(p[0], p[1], p[2], sa, ca);
                fadd(p[3], p[4], p[5], sb, cb2);
                hadd(p[6], p[7], sc, cc);
                u64 S0, cd; fadd(sa, sb, sc, S0, cd);
                u64 t2, ce; fadd(ca, cb2, cc, t2, ce);
                u64 S1, cf; hadd(cd, t2, S1, cf);
                u64 S2, S3; hadd(ce, cf, S2, S3);
                u64 Bge2 = S1 | S2 | S3;                  // B >= 2
                u64 Ble6 = ~((S2 & S1 & S0) | S3);        // B <= 6 (not 7, not 8)
                u64 cB   = Bge2 & Ble6;
                u64 c3, c4;
                if (step == 0) { c3 = ~(N & E & S);  c4 = ~(E & S & Wn); }
                else           { c3 = ~(N & E & Wn); c4 = ~(N & S & Wn); }
                nxt[lr][h4 + j] = c & ~(cB & A1 & c3 & c4);
            }
        }
        __syncthreads();
        u64 (*tmp)[LDSW] = cur; cur = nxt; nxt = tmp;
    };

    #pragma unroll 1
    for (int p = 0; p < NSUB / 2; ++p) {
        subiter(0);
        subiter(1);
    }

    // ---- expand band rows [r0, r0+BH) to int32 0/1, coalesced int4 stores ----
    const long slice_base = (long)z * HH * WWID;
    for (int e = t; e < BH * (WWID / 4); e += 512) {
        int rr  = e >> 7;          // / 128 int4s per row
        int x4  = e & 127;
        int gr  = r0 + rr;
        int lrr = gr - la;
        int col = x4 * 4;
        u64 w  = cur[lrr][col >> 6];
        int sh = col & 63;
        int4 f;
        f.x = (int)((w >> (sh + 0)) & 1ull);
        f.y = (int)((w >> (sh + 1)) & 1ull);
        f.z = (int)((w >> (sh + 2)) & 1ull);
        f.w = (int)((w >> (sh + 3)) & 1ull);
        *reinterpret_cast<int4*>(out + slice_base + (long)gr * WWID + col) = f;
    }
}

extern "C" void kernel_launch(void* const* d_in, const int* in_sizes, int n_in,
                              void* d_out, int out_size, void* d_ws, size_t ws_size,
                              hipStream_t stream) {
    const float* in  = (const float*)d_in[0];
    int*         out = (int*)d_out;
    u64*         bits = (u64*)d_ws;   // needs 64*512*8*8 = 2 MiB of scratch

    // 16,777,216 floats -> 262,144 packed u64 words
    pack_kernel<<<16384, 256, 0, stream>>>(in, bits);

    // 64 slices x 4 bands
    thin_kernel<<<DD * BANDS, 512, 0, stream>>>(bits, out);
}

// Round 6
// 135.124 us; speedup vs baseline: 1.0512x; 1.0512x over previous
//
#include <hip/hip_runtime.h>
#include <stdint.h>

// Problem geometry
#define DD    64          // slices
#define HH    512         // rows
#define WWID  512         // cols
#define WPR   8           // u64 words per row (512 bits)
#define NSUB  48          // 24 scan iters x 2 sub-iterations
#define BANDS 4           // row-bands per slice
#define BH    128         // output rows per band
#define HALO  52          // 48 (thinning) + 4 (closing: dilate 2 + erode 2)
#define MAXR  (BH + 2*HALO)   // 232 live rows max
#define ARR   (MAXR + 4)      // +2 guard rows each side = 236
#define PITCH 10              // guard word 0, live 1..8, guard word 9 (80B stride: 2-way banks)

typedef unsigned long long u64;

// ---------------- kernel 1: threshold + bit-pack via ballot ----------------
__global__ void pack_kernel(const float* __restrict__ in, u64* __restrict__ bits) {
    long gid  = (long)blockIdx.x * blockDim.x + threadIdx.x;
    long wv   = gid >> 6;
    int  lane = (int)(gid & 63);
    long base = wv * 256;
    #pragma unroll
    for (int k = 0; k < 4; ++k) {
        float v = in[base + (long)k * 64 + lane];
        u64 m = __ballot(v > 0.5f);
        if (lane == 0) bits[wv * 4 + k] = m;
    }
}

// bit-sliced full/half adders
__device__ __forceinline__ void fadd(u64 a, u64 b, u64 c, u64& s, u64& co) {
    u64 t = a ^ b;
    s  = t ^ c;
    co = (a & b) | (t & c);
}
__device__ __forceinline__ void hadd(u64 a, u64 b, u64& s, u64& co) {
    s = a ^ b; co = a & b;
}

// ---------------- kernel 2: closing + 48x thinning in LDS ----------------
// One block per (slice, band). 512 threads: 2 threads per row, 4 words each.
// Guard-padded LDS: all inner-loop reads unconditional (guards are true zeros
// at image borders; interior-band guard error lies outside the exact region).
__global__ __launch_bounds__(512, 1)
void thin_kernel(const u64* __restrict__ bits, int* __restrict__ out) {
    __shared__ u64 bufA[ARR][PITCH];
    __shared__ u64 bufB[ARR][PITCH];

    const int blk  = blockIdx.x;
    const int z    = blk >> 2;       // slice
    const int band = blk & 3;
    const int r0   = band * BH;      // first output row
    const int la   = (r0 - HALO > 0) ? (r0 - HALO) : 0;
    const int lb   = (r0 + BH + HALO < HH) ? (r0 + BH + HALO) : HH;
    const int nrows = lb - la;       // live rows (<= 232)
    const int ob0  = r0 - la;        // local output start (0 or 52)

    const int t  = threadIdx.x;
    const int lr = t >> 1;           // live row handled by this thread
    const int h4 = (t & 1) * 4;      // live word offset: 0 or 4
    const int ar = lr + 2;           // array row (2 guard rows at top)

    // ---- zero both buffers (guards must be 0 in both ping-pong buffers) ----
    {
        u64* fa = &bufA[0][0];
        u64* fb = &bufB[0][0];
        for (int i = t; i < ARR * PITCH; i += 512) { fa[i] = 0; fb[i] = 0; }
    }
    __syncthreads();

    // ---- load packed raw mask into bufA live area ----
    if (lr < nrows) {
        const u64* src = bits + ((long)(z * HH + la + lr)) * WPR + h4;
        ulonglong2 v0 = *reinterpret_cast<const ulonglong2*>(src);
        ulonglong2 v1 = *reinterpret_cast<const ulonglong2*>(src + 2);
        bufA[ar][h4 + 1] = v0.x;
        bufA[ar][h4 + 2] = v0.y;
        bufA[ar][h4 + 3] = v1.x;
        bufA[ar][h4 + 4] = v1.y;
    }
    __syncthreads();

    u64 (*cur)[PITCH] = bufA;
    u64 (*nxt)[PITCH] = bufB;

    // ---- closing: dilation then erosion with disk(2), unconditional reads ----
    #pragma unroll 1
    for (int phase = 0; phase < 2; ++phase) {   // 0 = dilation (OR), 1 = erosion (AND)
        if (lr < nrows) {
            u64 w[5][6];
            #pragma unroll
            for (int rr = 0; rr < 5; ++rr) {
                #pragma unroll
                for (int q = 0; q < 3; ++q) {
                    ulonglong2 v = *reinterpret_cast<const ulonglong2*>(&cur[ar - 2 + rr][h4 + 2 * q]);
                    w[rr][2 * q]     = v.x;
                    w[rr][2 * q + 1] = v.y;
                }
            }
            u64 res[4];
            #pragma unroll
            for (int jj = 0; jj < 4; ++jj) {
                u64 c  = w[2][jj + 1], pl = w[2][jj], pr = w[2][jj + 2];
                u64 l1 = (c << 1) | (pl >> 63);
                u64 l2 = (c << 2) | (pl >> 62);
                u64 r1 = (c >> 1) | (pr << 63);
                u64 r2 = (c >> 2) | (pr << 62);
                u64 u  = w[1][jj + 1];
                u64 ul = (u << 1) | (w[1][jj] >> 63);
                u64 ur = (u >> 1) | (w[1][jj + 2] << 63);
                u64 d  = w[3][jj + 1];
                u64 dl = (d << 1) | (w[3][jj] >> 63);
                u64 dr = (d >> 1) | (w[3][jj + 2] << 63);
                u64 u2 = w[0][jj + 1];
                u64 d2 = w[4][jj + 1];
                res[jj] = (phase == 0)
                    ? (c | l1 | l2 | r1 | r2 | u | ul | ur | d | dl | dr | u2 | d2)
                    : (c & l1 & l2 & r1 & r2 & u & ul & ur & d & dl & dr & u2 & d2);
            }
            #pragma unroll
            for (int jj = 0; jj < 4; ++jj) nxt[ar][h4 + 1 + jj] = res[jj];
        }
        __syncthreads();
        u64 (*tmp)[PITCH] = cur; cur = nxt; nxt = tmp;
    }

    // ---- 48 Zhang-Suen sub-iterations, bit-sliced, shrinking active range ----
    #pragma unroll 1
    for (int it = 0; it < NSUB / 2; ++it) {
        #pragma unroll
        for (int sub = 0; sub < 2; ++sub) {
            const int k  = 2 * it + sub + 1;           // 1..48
            const int hw = NSUB - k;                   // remaining halo width
            int lo = ob0 - hw;       if (lo < 0) lo = 0;
            int hi = ob0 + BH + hw;  if (hi > nrows) hi = nrows;
            if (lr >= lo && lr < hi) {
                u64 w[3][6];
                #pragma unroll
                for (int rr = 0; rr < 3; ++rr) {
                    #pragma unroll
                    for (int q = 0; q < 3; ++q) {
                        ulonglong2 v = *reinterpret_cast<const ulonglong2*>(&cur[ar - 1 + rr][h4 + 2 * q]);
                        w[rr][2 * q]     = v.x;
                        w[rr][2 * q + 1] = v.y;
                    }
                }
                u64 res[4];
                #pragma unroll
                for (int jj = 0; jj < 4; ++jj) {
                    u64 c  = w[1][jj + 1];
                    u64 N  = w[0][jj + 1];
                    u64 S  = w[2][jj + 1];
                    u64 E  = (w[1][jj + 1] >> 1) | (w[1][jj + 2] << 63);
                    u64 Wn = (w[1][jj + 1] << 1) | (w[1][jj]     >> 63);
                    u64 NE = (w[0][jj + 1] >> 1) | (w[0][jj + 2] << 63);
                    u64 NW = (w[0][jj + 1] << 1) | (w[0][jj]     >> 63);
                    u64 SE = (w[2][jj + 1] >> 1) | (w[2][jj + 2] << 63);
                    u64 SW = (w[2][jj + 1] << 1) | (w[2][jj]    >> 63);
                    // P2..P9 = N,NE,E,SE,S,SW,W,NW
                    u64 p[8] = {N, NE, E, SE, S, SW, Wn, NW};
                    // A == 1: exactly one 0->1 transition around the ring
                    u64 one = 0, two = 0;
                    #pragma unroll
                    for (int q = 0; q < 8; ++q) {
                        u64 tk = ~p[q] & p[(q + 1) & 7];
                        two |= one & tk;
                        one |= tk;
                    }
                    u64 A1 = one & ~two;
                    // B = popcount(P2..P9) per pixel, bit-sliced CSA
                    u64 sa, ca, sb, cb2, sc, cc;
                    fadd(p[0], p[1], p[2], sa, ca);
                    fadd(p[3], p[4], p[5], sb, cb2);
                    hadd(p[6], p[7], sc, cc);
                    u64 S0, cd; fadd(sa, sb, sc, S0, cd);
                    u64 t2, ce; fadd(ca, cb2, cc, t2, ce);
                    u64 S1, cf; hadd(cd, t2, S1, cf);
                    u64 S2, S3; hadd(ce, cf, S2, S3);
                    u64 Bge2 = S1 | S2 | S3;                  // B >= 2
                    u64 Ble6 = ~((S2 & S1 & S0) | S3);        // B <= 6
                    u64 cB   = Bge2 & Ble6;
                    u64 c3, c4;
                    if (sub == 0) { c3 = ~(N & E & S);  c4 = ~(E & S & Wn); }
                    else          { c3 = ~(N & E & Wn); c4 = ~(N & S & Wn); }
                    res[jj] = c & ~(cB & A1 & c3 & c4);
                }
                #pragma unroll
                for (int jj = 0; jj < 4; ++jj) nxt[ar][h4 + 1 + jj] = res[jj];
            }
            __syncthreads();
            u64 (*tmp)[PITCH] = cur; cur = nxt; nxt = tmp;
        }
    }

    // ---- expand band rows [r0, r0+BH) to int32 0/1, coalesced int4 stores ----
    const long slice_base = (long)z * HH * WWID;
    for (int e = t; e < BH * (WWID / 4); e += 512) {
        int rr  = e >> 7;          // / 128 int4s per row
        int x4  = e & 127;
        int gr  = r0 + rr;
        int arr = (gr - la) + 2;
        int col = x4 * 4;
        u64 w  = cur[arr][1 + (col >> 6)];
        int sh = col & 63;
        int4 f;
        f.x = (int)((w >> (sh + 0)) & 1ull);
        f.y = (int)((w >> (sh + 1)) & 1ull);
        f.z = (int)((w >> (sh + 2)) & 1ull);
        f.w = (int)((w >> (sh + 3)) & 1ull);
        *reinterpret_cast<int4*>(out + slice_base + (long)gr * WWID + col) = f;
    }
}

extern "C" void kernel_launch(void* const* d_in, const int* in_sizes, int n_in,
                              void* d_out, int out_size, void* d_ws, size_t ws_size,
                              hipStream_t stream) {
    const float* in   = (const float*)d_in[0];
    int*         out  = (int*)d_out;
    u64*         bits = (u64*)d_ws;   // 64*512*8*8 = 2 MiB scratch

    pack_kernel<<<16384, 256, 0, stream>>>(in, bits);
    thin_kernel<<<DD * BANDS, 512, 0, stream>>>(bits, out);
}